// Round 1
// baseline (589.119 us; speedup 1.0000x reference)
//
#include <hip/hip_runtime.h>
#include <hip/hip_bf16.h>
#include <cstdint>

#define D 128     // feature dim
#define MB 64     // nodes per block in precompute

__device__ __forceinline__ float bf2f(unsigned short u) {
    return __uint_as_float(((unsigned int)u) << 16);
}
__device__ __forceinline__ unsigned short f2bf(float f) {
    unsigned int x = __float_as_uint(f);
    x = (x + 0x7FFFu + ((x >> 16) & 1u)) >> 16;   // RNE
    return (unsigned short)x;
}

// Kernel A: A[n] = x[n] @ W1[0:128,:],  B[n] = x[n] @ W1[128:256,:]  (bf16 out)
__global__ __launch_bounds__(256) void node_mlp_kernel(
    const float* __restrict__ x, const float* __restrict__ W1,
    unsigned short* __restrict__ Aout, unsigned short* __restrict__ Bout, int N)
{
    __shared__ float xT[D][MB + 4];   // transposed tile; stride 68 floats = 272B (16B-aligned)
    const int t = threadIdx.x;
    const int blockStart = blockIdx.x * MB;

    // stage x tile transposed: 4 threads per node, 32 floats each
    {
        const int m = t >> 2;               // 0..63
        const int kb = (t & 3) * 32;        // k base
        const int node = blockStart + m;
        const float* row = x + (size_t)node * D;
        #pragma unroll
        for (int i = 0; i < 8; ++i) {
            const int k = kb + i * 4;
            float4 v = make_float4(0.f, 0.f, 0.f, 0.f);
            if (node < N) v = *reinterpret_cast<const float4*>(row + k);
            xT[k + 0][m] = v.x;
            xT[k + 1][m] = v.y;
            xT[k + 2][m] = v.z;
            xT[k + 3][m] = v.w;
        }
    }
    __syncthreads();

    const int tx = t & 31;          // output col group: jj0 = tx*8 in 0..255 (A cols then B cols)
    const int ty = t >> 5;          // node group: m0 = ty*8
    const int jj0 = tx * 8;
    const int m0 = ty * 8;
    const int half = jj0 >> 7;      // 0 -> A (W1 rows 0..127), 1 -> B (W1 rows 128..255)
    const int j0 = jj0 & 127;
    const float* Wbase = W1 + ((size_t)half * 128) * D + j0;

    float acc[8][8];
    #pragma unroll
    for (int i = 0; i < 8; ++i)
        #pragma unroll
        for (int c = 0; c < 8; ++c) acc[i][c] = 0.f;

    #pragma unroll 2
    for (int k = 0; k < D; ++k) {
        const float4 xa = *reinterpret_cast<const float4*>(&xT[k][m0]);
        const float4 xb = *reinterpret_cast<const float4*>(&xT[k][m0 + 4]);
        const float4 wa = *reinterpret_cast<const float4*>(Wbase + (size_t)k * D);
        const float4 wb = *reinterpret_cast<const float4*>(Wbase + (size_t)k * D + 4);
        const float xs[8] = {xa.x, xa.y, xa.z, xa.w, xb.x, xb.y, xb.z, xb.w};
        const float ws[8] = {wa.x, wa.y, wa.z, wa.w, wb.x, wb.y, wb.z, wb.w};
        #pragma unroll
        for (int i = 0; i < 8; ++i)
            #pragma unroll
            for (int c = 0; c < 8; ++c)
                acc[i][c] = fmaf(xs[i], ws[c], acc[i][c]);
    }

    unsigned short* Out = half ? Bout : Aout;
    #pragma unroll
    for (int i = 0; i < 8; ++i) {
        const int node = blockStart + m0 + i;
        if (node >= N) break;
        unsigned short tmp[8];
        #pragma unroll
        for (int c = 0; c < 8; ++c) tmp[c] = f2bf(acc[i][c]);
        *reinterpret_cast<uint4*>(Out + (size_t)node * D + j0) =
            *reinterpret_cast<const uint4*>(tmp);
    }
}

// Kernel B: one wave (64 lanes) per edge. lane l handles dims 2l, 2l+1.
__global__ __launch_bounds__(256) void edge_kernel(
    const unsigned short* __restrict__ A, const unsigned short* __restrict__ Bt,
    const int* __restrict__ src, const int* __restrict__ dst,
    const float* __restrict__ b1, const float* __restrict__ W2,
    const float* __restrict__ b2,
    const float* __restrict__ u_gate, const float* __restrict__ u_bern,
    float* __restrict__ out, int E)
{
    const int gid = blockIdx.x * blockDim.x + threadIdx.x;
    const int e = gid >> 6;
    const int lane = threadIdx.x & 63;
    if (e >= E) return;

    const int s = src[e];
    const int d = dst[e];

    const ushort2 av = *reinterpret_cast<const ushort2*>(A  + (size_t)s * D + lane * 2);
    const ushort2 bv = *reinterpret_cast<const ushort2*>(Bt + (size_t)d * D + lane * 2);
    const float2  b1v = *reinterpret_cast<const float2*>(b1 + lane * 2);
    const float2  w2v = *reinterpret_cast<const float2*>(W2 + lane * 2);

    const float h0 = fmaxf(bf2f(av.x) + bf2f(bv.x) + b1v.x, 0.f);
    const float h1 = fmaxf(bf2f(av.y) + bf2f(bv.y) + b1v.y, 0.f);
    float p = fmaf(h0, w2v.x, h1 * w2v.y);

    #pragma unroll
    for (int off = 32; off >= 1; off >>= 1)
        p += __shfl_xor(p, off, 64);

    const float logit = p + b2[0];

    // gumbel-sigmoid gate
    const float ug  = u_gate[e];
    const float eps = fmaf(-0.9998f, ug, 0.9999f);           // (BIAS-(1-BIAS))*u + (1-BIAS)
    const float g   = logf(eps) - log1pf(-eps) + logit;       // TEMP_GATE = 1
    const float ew  = 1.f / (1.f + expf(-g));                 // edge_weight

    // RelaxedBernoulli(temp=0.9).rsample
    const float att = fminf(fmaxf(ew, 0.01f), 0.99f);
    const float bl  = logf(att) - log1pf(-att);
    const float ub  = fminf(fmaxf(u_bern[e], 1e-7f), 1.f - 1e-7f);
    const float arg = (bl + logf(ub) - log1pf(-ub)) * (1.0f / 0.9f);
    const float wv  = 1.f / (1.f + expf(-arg));

    // mask = (w > 0): sigmoid > 0 always; if it underflows to 0, w*mask == w too.
    if (lane == 0) out[e] = wv;
}

extern "C" void kernel_launch(void* const* d_in, const int* in_sizes, int n_in,
                              void* d_out, int out_size, void* d_ws, size_t ws_size,
                              hipStream_t stream)
{
    const float* node_emb = (const float*)d_in[0];
    const int*   src      = (const int*)d_in[1];
    const int*   dst      = (const int*)d_in[2];
    const float* W1       = (const float*)d_in[3];
    const float* b1       = (const float*)d_in[4];
    const float* W2       = (const float*)d_in[5];
    const float* b2       = (const float*)d_in[6];
    const float* u_gate   = (const float*)d_in[7];
    const float* u_bern   = (const float*)d_in[8];
    float* out = (float*)d_out;

    const int N = in_sizes[0] / D;
    const int E = in_sizes[1];

    unsigned short* A = (unsigned short*)d_ws;
    unsigned short* B = A + (size_t)N * D;

    const dim3 gridA((N + MB - 1) / MB);
    node_mlp_kernel<<<gridA, 256, 0, stream>>>(node_emb, W1, A, B, N);

    const long long totalThreads = (long long)E * 64;
    const int blocksB = (int)((totalThreads + 255) / 256);
    edge_kernel<<<blocksB, 256, 0, stream>>>(A, B, src, dst, b1, W2, b2,
                                             u_gate, u_bern, out, E);
}

// Round 2
// 251.452 us; speedup vs baseline: 2.3429x; 2.3429x over previous
//
#include <hip/hip_runtime.h>
#include <hip/hip_bf16.h>
#include <cstdint>

#define D 128     // feature dim
#define MB 64     // nodes per block in precompute

__device__ __forceinline__ unsigned short f2bf(float f) {
    unsigned int x = __float_as_uint(f);
    x = (x + 0x7FFFu + ((x >> 16) & 1u)) >> 16;   // RNE
    return (unsigned short)x;
}

// Kernel A: A[n] = x[n] @ W1[0:128,:] + b1,  B[n] = x[n] @ W1[128:256,:]  (bf16 out)
__global__ __launch_bounds__(256) void node_mlp_kernel(
    const float* __restrict__ x, const float* __restrict__ W1,
    const float* __restrict__ b1,
    unsigned short* __restrict__ Aout, unsigned short* __restrict__ Bout, int N)
{
    __shared__ float xT[D][MB + 4];   // transposed tile
    const int t = threadIdx.x;
    const int blockStart = blockIdx.x * MB;

    // stage x tile transposed: 4 threads per node, 32 floats each
    {
        const int m = t >> 2;               // 0..63
        const int kb = (t & 3) * 32;        // k base
        const int node = blockStart + m;
        const float* row = x + (size_t)node * D;
        #pragma unroll
        for (int i = 0; i < 8; ++i) {
            const int k = kb + i * 4;
            float4 v = make_float4(0.f, 0.f, 0.f, 0.f);
            if (node < N) v = *reinterpret_cast<const float4*>(row + k);
            xT[k + 0][m] = v.x;
            xT[k + 1][m] = v.y;
            xT[k + 2][m] = v.z;
            xT[k + 3][m] = v.w;
        }
    }
    __syncthreads();

    const int tx = t & 31;          // output col group: jj0 = tx*8 in 0..255
    const int ty = t >> 5;          // node group: m0 = ty*8
    const int jj0 = tx * 8;
    const int m0 = ty * 8;
    const int half = jj0 >> 7;      // 0 -> A (W1 rows 0..127), 1 -> B (W1 rows 128..255)
    const int j0 = jj0 & 127;
    const float* Wbase = W1 + ((size_t)half * 128) * D + j0;

    float acc[8][8];
    #pragma unroll
    for (int i = 0; i < 8; ++i)
        #pragma unroll
        for (int c = 0; c < 8; ++c) acc[i][c] = 0.f;

    #pragma unroll 2
    for (int k = 0; k < D; ++k) {
        const float4 xa = *reinterpret_cast<const float4*>(&xT[k][m0]);
        const float4 xb = *reinterpret_cast<const float4*>(&xT[k][m0 + 4]);
        const float4 wa = *reinterpret_cast<const float4*>(Wbase + (size_t)k * D);
        const float4 wb = *reinterpret_cast<const float4*>(Wbase + (size_t)k * D + 4);
        const float xs[8] = {xa.x, xa.y, xa.z, xa.w, xb.x, xb.y, xb.z, xb.w};
        const float ws[8] = {wa.x, wa.y, wa.z, wa.w, wb.x, wb.y, wb.z, wb.w};
        #pragma unroll
        for (int i = 0; i < 8; ++i)
            #pragma unroll
            for (int c = 0; c < 8; ++c)
                acc[i][c] = fmaf(xs[i], ws[c], acc[i][c]);
    }

    // fold b1 into the A table (h = relu(A'[s] + B[d]) later)
    float bias[8] = {0,0,0,0,0,0,0,0};
    if (half == 0) {
        const float4 bb0 = *reinterpret_cast<const float4*>(b1 + j0);
        const float4 bb1 = *reinterpret_cast<const float4*>(b1 + j0 + 4);
        bias[0] = bb0.x; bias[1] = bb0.y; bias[2] = bb0.z; bias[3] = bb0.w;
        bias[4] = bb1.x; bias[5] = bb1.y; bias[6] = bb1.z; bias[7] = bb1.w;
    }

    unsigned short* Out = half ? Bout : Aout;
    #pragma unroll
    for (int i = 0; i < 8; ++i) {
        const int node = blockStart + m0 + i;
        if (node >= N) break;
        unsigned short tmp[8];
        #pragma unroll
        for (int c = 0; c < 8; ++c) tmp[c] = f2bf(acc[i][c] + bias[c]);
        *reinterpret_cast<uint4*>(Out + (size_t)node * D + j0) =
            *reinterpret_cast<const uint4*>(tmp);
    }
}

__device__ __forceinline__ float acc_pair(uint32_t wa, uint32_t wb,
                                          float w2lo, float w2hi, float p) {
    const float alo = __uint_as_float(wa << 16);
    const float ahi = __uint_as_float(wa & 0xffff0000u);
    const float blo = __uint_as_float(wb << 16);
    const float bhi = __uint_as_float(wb & 0xffff0000u);
    const float h0 = fmaxf(alo + blo, 0.f);
    const float h1 = fmaxf(ahi + bhi, 0.f);
    p = fmaf(h0, w2lo, p);
    p = fmaf(h1, w2hi, p);
    return p;
}

// Kernel B1: 8 lanes per edge; lane `sub` handles dims [sub*16, sub*16+16)
__global__ __launch_bounds__(256) void edge_dot_kernel(
    const unsigned short* __restrict__ A, const unsigned short* __restrict__ Bt,
    const int* __restrict__ src, const int* __restrict__ dst,
    const float* __restrict__ W2, float* __restrict__ logits, int E)
{
    const int gid = blockIdx.x * blockDim.x + threadIdx.x;
    const int e = gid >> 3;
    if (e >= E) return;
    const int sub = threadIdx.x & 7;

    const int s = src[e];
    const int d = dst[e];

    const uint4* Ap = reinterpret_cast<const uint4*>(A  + (size_t)s * D + sub * 16);
    const uint4* Bp = reinterpret_cast<const uint4*>(Bt + (size_t)d * D + sub * 16);
    const float4* Wp = reinterpret_cast<const float4*>(W2 + sub * 16);

    const uint4 a0 = Ap[0], a1 = Ap[1];
    const uint4 c0 = Bp[0], c1 = Bp[1];
    const float4 w0 = Wp[0], w1 = Wp[1], w2 = Wp[2], w3 = Wp[3];

    float p = 0.f;
    p = acc_pair(a0.x, c0.x, w0.x, w0.y, p);
    p = acc_pair(a0.y, c0.y, w0.z, w0.w, p);
    p = acc_pair(a0.z, c0.z, w1.x, w1.y, p);
    p = acc_pair(a0.w, c0.w, w1.z, w1.w, p);
    p = acc_pair(a1.x, c1.x, w2.x, w2.y, p);
    p = acc_pair(a1.y, c1.y, w2.z, w2.w, p);
    p = acc_pair(a1.z, c1.z, w3.x, w3.y, p);
    p = acc_pair(a1.w, c1.w, w3.z, w3.w, p);

    // reduce across the 8-lane group
    p += __shfl_xor(p, 1, 64);
    p += __shfl_xor(p, 2, 64);
    p += __shfl_xor(p, 4, 64);

    if (sub == 0) logits[e] = p;
}

// Kernel B2: scalar tail, one thread per edge (fully coalesced)
__global__ __launch_bounds__(256) void tail_kernel(
    const float* __restrict__ logits, const float* __restrict__ b2,
    const float* __restrict__ u_gate, const float* __restrict__ u_bern,
    float* __restrict__ out, int E)
{
    const int e = blockIdx.x * blockDim.x + threadIdx.x;
    if (e >= E) return;

    const float logit = logits[e] + b2[0];

    // gumbel-sigmoid gate
    const float ug  = u_gate[e];
    const float eps = fmaf(-0.9998f, ug, 0.9999f);           // (BIAS-(1-BIAS))*u + (1-BIAS)
    const float g   = logf(eps) - log1pf(-eps) + logit;       // TEMP_GATE = 1
    const float ew  = 1.f / (1.f + expf(-g));                 // edge_weight

    // RelaxedBernoulli(temp=0.9).rsample
    const float att = fminf(fmaxf(ew, 0.01f), 0.99f);
    const float bl  = logf(att) - log1pf(-att);
    const float ub  = fminf(fmaxf(u_bern[e], 1e-7f), 1.f - 1e-7f);
    const float arg = (bl + logf(ub) - log1pf(-ub)) * (1.0f / 0.9f);
    const float wv  = 1.f / (1.f + expf(-arg));

    // mask = (w > 0): sigmoid > 0 always; if it underflows to 0, w*mask == w.
    out[e] = wv;
}

extern "C" void kernel_launch(void* const* d_in, const int* in_sizes, int n_in,
                              void* d_out, int out_size, void* d_ws, size_t ws_size,
                              hipStream_t stream)
{
    const float* node_emb = (const float*)d_in[0];
    const int*   src      = (const int*)d_in[1];
    const int*   dst      = (const int*)d_in[2];
    const float* W1       = (const float*)d_in[3];
    const float* b1       = (const float*)d_in[4];
    const float* W2       = (const float*)d_in[5];
    const float* b2       = (const float*)d_in[6];
    const float* u_gate   = (const float*)d_in[7];
    const float* u_bern   = (const float*)d_in[8];
    float* out = (float*)d_out;

    const int N = in_sizes[0] / D;
    const int E = in_sizes[1];

    unsigned short* A = (unsigned short*)d_ws;
    unsigned short* B = A + (size_t)N * D;
    float* logits = (float*)(B + (size_t)N * D);

    const dim3 gridA((N + MB - 1) / MB);
    node_mlp_kernel<<<gridA, 256, 0, stream>>>(node_emb, W1, b1, A, B, N);

    const long long dotThreads = (long long)E * 8;
    const int blocksDot = (int)((dotThreads + 255) / 256);
    edge_dot_kernel<<<blocksDot, 256, 0, stream>>>(A, B, src, dst, W2, logits, E);

    const int blocksTail = (E + 255) / 256;
    tail_kernel<<<blocksTail, 256, 0, stream>>>(logits, b2, u_gate, u_bern, out, E);
}

// Round 3
// 200.273 us; speedup vs baseline: 2.9416x; 1.2555x over previous
//
#include <hip/hip_runtime.h>
#include <hip/hip_bf16.h>
#include <cstdint>

#define D  128    // feature dim / MLP hidden dim
#define NT 256    // combined table row: cols 0-127 = A-part, 128-255 = B-part

typedef __attribute__((ext_vector_type(8))) short bf16x8;
typedef __attribute__((ext_vector_type(4))) float f32x4;

// pack two fp32 -> two bf16 (round-half-up): 2 adds + 1 v_perm
__device__ __forceinline__ unsigned int packbf(float lo, float hi) {
    const unsigned int ulo = __float_as_uint(lo) + 0x8000u;
    const unsigned int uhi = __float_as_uint(hi) + 0x8000u;
    // dst = (uhi.hi16 << 16) | ulo.hi16
    return __builtin_amdgcn_perm(uhi, ulo, 0x07060302);
}

// ---------------------------------------------------------------------------
// Node projection via MFMA: T[n][jj] = sum_k x[n][k] * W1cat[k][jj]  (bf16)
//   W1cat[k][jj] = W1[k][jj]        for jj < 128   (A-part)
//                = W1[128+k][jj-128] for jj >= 128  (B-part)
// Each wave: owns one col-half (128 cols = 8 col-groups), W1 frags in regs,
// loops over 16-node chunks. x frags are the MFMA B-operand: contiguous 32B
// per lane straight from global. No LDS, no barriers.
// ---------------------------------------------------------------------------
__global__ __launch_bounds__(256, 2) void node_mlp_mfma(
    const float* __restrict__ x, const float* __restrict__ W1,
    unsigned short* __restrict__ T, int N)
{
    const int lane = threadIdx.x & 63;
    const int wid  = (blockIdx.x * blockDim.x + threadIdx.x) >> 6;  // 0..2047
    const int half = wid & 1;           // col-half: 0 -> jj 0..127, 1 -> jj 128..255
    const int strip = wid >> 1;         // 0..1023
    const int lr = lane & 15;           // node-within-chunk / col-within-group
    const int lg = lane >> 4;           // k-subgroup (0..3)

    const int NCH = (N + 15) >> 4;      // 16-node chunks

    // ---- W1 fragments: A-operand, M=16 cols (jj), K=32. Lane: row=lr, k=8*lg+i
    bf16x8 wf[8][4];
    #pragma unroll
    for (int cg = 0; cg < 8; ++cg) {
        #pragma unroll
        for (int ks = 0; ks < 4; ++ks) {
            const int k0 = (half ? 128 : 0) + 32 * ks + 8 * lg;
            const float* wp = W1 + (size_t)k0 * D + cg * 16 + lr;
            float l0 = wp[0*D], l1 = wp[1*D], l2 = wp[2*D], l3 = wp[3*D];
            float l4 = wp[4*D], l5 = wp[5*D], l6 = wp[6*D], l7 = wp[7*D];
            uint4 u;
            u.x = packbf(l0, l1); u.y = packbf(l2, l3);
            u.z = packbf(l4, l5); u.w = packbf(l6, l7);
            wf[cg][ks] = __builtin_bit_cast(bf16x8, u);
        }
    }

    // ---- main loop over node chunks (grid-strided by 1024 strips)
    int c = strip;
    if (c >= NCH) return;

    size_t row = (size_t)(c * 16 + lr);
    if (row > (size_t)(N - 1)) row = (size_t)(N - 1);
    const float4* pf = reinterpret_cast<const float4*>(x + row * D + 8 * lg);
    float4 r0 = pf[0],  r1 = pf[1],  r2 = pf[8],  r3 = pf[9];
    float4 r4 = pf[16], r5 = pf[17], r6 = pf[24], r7 = pf[25];

    while (c < NCH) {
        // convert current chunk's x to bf16 fragments (B-operand: col=node, k=8*lg+i)
        bf16x8 xf[4];
        {
            uint4 u;
            u.x = packbf(r0.x, r0.y); u.y = packbf(r0.z, r0.w);
            u.z = packbf(r1.x, r1.y); u.w = packbf(r1.z, r1.w);
            xf[0] = __builtin_bit_cast(bf16x8, u);
            u.x = packbf(r2.x, r2.y); u.y = packbf(r2.z, r2.w);
            u.z = packbf(r3.x, r3.y); u.w = packbf(r3.z, r3.w);
            xf[1] = __builtin_bit_cast(bf16x8, u);
            u.x = packbf(r4.x, r4.y); u.y = packbf(r4.z, r4.w);
            u.z = packbf(r5.x, r5.y); u.w = packbf(r5.z, r5.w);
            xf[2] = __builtin_bit_cast(bf16x8, u);
            u.x = packbf(r6.x, r6.y); u.y = packbf(r6.z, r6.w);
            u.z = packbf(r7.x, r7.y); u.w = packbf(r7.z, r7.w);
            xf[3] = __builtin_bit_cast(bf16x8, u);
        }

        // prefetch next chunk
        const int cn = c + 1024;
        {
            size_t row2 = (size_t)(cn * 16 + lr);
            if (row2 > (size_t)(N - 1)) row2 = (size_t)(N - 1);
            pf = reinterpret_cast<const float4*>(x + row2 * D + 8 * lg);
        }
        float4 t0 = pf[0],  t1 = pf[1],  t2 = pf[8],  t3 = pf[9];
        float4 t4 = pf[16], t5 = pf[17], t6 = pf[24], t7 = pf[25];

        // MFMA: acc[cg] over 4 K-steps
        f32x4 acc[8];
        #pragma unroll
        for (int cg = 0; cg < 8; ++cg) acc[cg] = (f32x4){0.f, 0.f, 0.f, 0.f};
        #pragma unroll
        for (int ks = 0; ks < 4; ++ks) {
            #pragma unroll
            for (int cg = 0; cg < 8; ++cg) {
                acc[cg] = __builtin_amdgcn_mfma_f32_16x16x32_bf16(
                    wf[cg][ks], xf[ks], acc[cg], 0, 0, 0);
            }
        }

        // store: lane holds node = c*16+lr, jj = half*128 + cg*16 + 4*lg + r
        const int node = c * 16 + lr;
        if (node < N) {
            unsigned short* orow = T + (size_t)node * NT + half * 128 + lg * 4;
            #pragma unroll
            for (int cg = 0; cg < 8; ++cg) {
                uint2 o;
                o.x = packbf(acc[cg][0], acc[cg][1]);
                o.y = packbf(acc[cg][2], acc[cg][3]);
                *reinterpret_cast<uint2*>(orow + cg * 16) = o;
            }
        }

        r0 = t0; r1 = t1; r2 = t2; r3 = t3;
        r4 = t4; r5 = t5; r6 = t6; r7 = t7;
        c = cn;
    }
}

// ---------------------------------------------------------------------------
// Edge kernel: 8 lanes/edge, dims sub*16..sub*16+15 per lane; b1 re-added here;
// gumbel/bernoulli tail fused on lane sub==0.
// ---------------------------------------------------------------------------
__device__ __forceinline__ float acc_pair(uint32_t wa, uint32_t wb,
                                          float blo, float bhi,
                                          float w2lo, float w2hi, float p) {
    const float alo = __uint_as_float(wa << 16);
    const float ahi = __uint_as_float(wa & 0xffff0000u);
    const float clo = __uint_as_float(wb << 16);
    const float chi = __uint_as_float(wb & 0xffff0000u);
    const float h0 = fmaxf(alo + clo + blo, 0.f);
    const float h1 = fmaxf(ahi + chi + bhi, 0.f);
    p = fmaf(h0, w2lo, p);
    p = fmaf(h1, w2hi, p);
    return p;
}

__global__ __launch_bounds__(256) void edge_kernel(
    const unsigned short* __restrict__ T,
    const int* __restrict__ src, const int* __restrict__ dst,
    const float* __restrict__ b1, const float* __restrict__ W2,
    const float* __restrict__ b2,
    const float* __restrict__ u_gate, const float* __restrict__ u_bern,
    float* __restrict__ out, int E)
{
    const int gid = blockIdx.x * blockDim.x + threadIdx.x;
    const int e = gid >> 3;
    if (e >= E) return;
    const int sub = threadIdx.x & 7;

    const int s = src[e];
    const int d = dst[e];

    const uint4* Ap = reinterpret_cast<const uint4*>(T + (size_t)s * NT + sub * 16);
    const uint4* Bp = reinterpret_cast<const uint4*>(T + (size_t)d * NT + 128 + sub * 16);
    const float4* Bv = reinterpret_cast<const float4*>(b1 + sub * 16);
    const float4* Wv = reinterpret_cast<const float4*>(W2 + sub * 16);

    const uint4 a0 = Ap[0], a1 = Ap[1];
    const uint4 c0 = Bp[0], c1 = Bp[1];
    const float4 bb0 = Bv[0], bb1 = Bv[1], bb2 = Bv[2], bb3 = Bv[3];
    const float4 w0 = Wv[0], w1 = Wv[1], w2 = Wv[2], w3 = Wv[3];

    float p = 0.f;
    p = acc_pair(a0.x, c0.x, bb0.x, bb0.y, w0.x, w0.y, p);
    p = acc_pair(a0.y, c0.y, bb0.z, bb0.w, w0.z, w0.w, p);
    p = acc_pair(a0.z, c0.z, bb1.x, bb1.y, w1.x, w1.y, p);
    p = acc_pair(a0.w, c0.w, bb1.z, bb1.w, w1.z, w1.w, p);
    p = acc_pair(a1.x, c1.x, bb2.x, bb2.y, w2.x, w2.y, p);
    p = acc_pair(a1.y, c1.y, bb2.z, bb2.w, w2.z, w2.w, p);
    p = acc_pair(a1.z, c1.z, bb3.x, bb3.y, w3.x, w3.y, p);
    p = acc_pair(a1.w, c1.w, bb3.z, bb3.w, w3.z, w3.w, p);

    // reduce across the 8-lane group
    p += __shfl_xor(p, 1, 64);
    p += __shfl_xor(p, 2, 64);
    p += __shfl_xor(p, 4, 64);

    if (sub == 0) {
        const float logit = p + b2[0];

        // gumbel-sigmoid gate
        const float ug  = u_gate[e];
        const float eps = fmaf(-0.9998f, ug, 0.9999f);        // (BIAS-(1-BIAS))*u + (1-BIAS)
        const float g   = logf(eps) - log1pf(-eps) + logit;    // TEMP_GATE = 1
        const float ew  = 1.f / (1.f + expf(-g));              // edge_weight

        // RelaxedBernoulli(temp=0.9).rsample
        const float att = fminf(fmaxf(ew, 0.01f), 0.99f);
        const float bl  = logf(att) - log1pf(-att);
        const float ub  = fminf(fmaxf(u_bern[e], 1e-7f), 1.f - 1e-7f);
        const float arg = (bl + logf(ub) - log1pf(-ub)) * (1.0f / 0.9f);
        const float wv  = 1.f / (1.f + expf(-arg));

        // mask = (w > 0): sigmoid > 0 always; if it underflows to 0, w*mask == w.
        out[e] = wv;
    }
}

extern "C" void kernel_launch(void* const* d_in, const int* in_sizes, int n_in,
                              void* d_out, int out_size, void* d_ws, size_t ws_size,
                              hipStream_t stream)
{
    const float* node_emb = (const float*)d_in[0];
    const int*   src      = (const int*)d_in[1];
    const int*   dst      = (const int*)d_in[2];
    const float* W1       = (const float*)d_in[3];
    const float* b1       = (const float*)d_in[4];
    const float* W2       = (const float*)d_in[5];
    const float* b2       = (const float*)d_in[6];
    const float* u_gate   = (const float*)d_in[7];
    const float* u_bern   = (const float*)d_in[8];
    float* out = (float*)d_out;

    const int N = in_sizes[0] / D;
    const int E = in_sizes[1];

    unsigned short* T = (unsigned short*)d_ws;  // [N][256] bf16

    // 512 blocks x 4 waves = 2048 waves = 1024 strips x 2 col-halves
    node_mlp_mfma<<<512, 256, 0, stream>>>(node_emb, W1, T, N);

    const long long dotThreads = (long long)E * 8;
    const int blocksE = (int)((dotThreads + 255) / 256);
    edge_kernel<<<blocksE, 256, 0, stream>>>(T, src, dst, b1, W2, b2,
                                             u_gate, u_bern, out, E);
}